// Round 3
// baseline (494.202 us; speedup 1.0000x reference)
//
#include <hip/hip_runtime.h>
#include <hip/hip_bf16.h>

using bf16 = __hip_bfloat16;
typedef __attribute__((ext_vector_type(8))) short short8;
typedef __attribute__((ext_vector_type(4))) float f32x4;

#define AS1 __attribute__((address_space(1)))
#define AS3 __attribute__((address_space(3)))

__device__ __forceinline__ void gload_lds16(const void* g, void* l) {
  __builtin_amdgcn_global_load_lds((const AS1 unsigned int*)g,
                                   (AS3 unsigned int*)l, 16, 0, 0);
}

// ---------------------------------------------------------------- convert f32 -> bf16
__global__ __launch_bounds__(256) void k_convert(const float* __restrict__ src,
                                                 bf16* __restrict__ dst, int n4) {
  int i = blockIdx.x * 256 + threadIdx.x;
  if (i >= n4) return;
  float4 v = reinterpret_cast<const float4*>(src)[i];
  alignas(8) bf16 o[4] = {__float2bfloat16(v.x), __float2bfloat16(v.y),
                          __float2bfloat16(v.z), __float2bfloat16(v.w)};
  *reinterpret_cast<uint2*>(dst + (size_t)i * 4) = *reinterpret_cast<uint2*>(o);
}

// ------------------------------------------- transpose+convert W (k,n) -> WT bf16 (n,k)
__global__ __launch_bounds__(256) void k_wtrans(
    const float* __restrict__ W0, const float* __restrict__ W1,
    const float* __restrict__ W2, const float* __restrict__ W3,
    bf16* __restrict__ T0, bf16* __restrict__ T1,
    bf16* __restrict__ T2, bf16* __restrict__ T3) {
  __shared__ float tile[64][65];
  const float* W; bf16* T;
  switch (blockIdx.z) {
    case 0: W = W0; T = T0; break;
    case 1: W = W1; T = T1; break;
    case 2: W = W2; T = T2; break;
    default: W = W3; T = T3; break;
  }
  const int k0 = blockIdx.x * 64, n0 = blockIdx.y * 64;
  const int r = threadIdx.x >> 6, c = threadIdx.x & 63;
#pragma unroll
  for (int i = 0; i < 16; i++)
    tile[r + i * 4][c] = W[(size_t)(k0 + r + i * 4) * 1024 + n0 + c];
  __syncthreads();
#pragma unroll
  for (int i = 0; i < 16; i++)
    T[(size_t)(n0 + r + i * 4) * 1024 + k0 + c] = __float2bfloat16(tile[c][r + i * 4]);
}

// ---------------------------------------------------------------- GEMM: C = A @ BT^T
// A: M x K bf16 row-major; BT: N x K bf16 row-major. 128x128 tile, BK=32, 4 waves.
template <int OUT_F32>
__global__ __launch_bounds__(256) void k_gemm_bt(
    const bf16* __restrict__ A, const bf16* __restrict__ BT,
    const float* __restrict__ bias, const float* __restrict__ scale,
    void* __restrict__ Cout, int M, int N, int K) {
  __shared__ alignas(16) bf16 sA[128 * 32];
  __shared__ alignas(16) bf16 sB[128 * 32];
  const int lane = threadIdx.x & 63;
  const int wid = threadIdx.x >> 6;
  const int wr = wid >> 1, wc = wid & 1;
  const int m0 = blockIdx.x * 128;
  const int n0 = blockIdx.y * 128;

  f32x4 acc[4][4];
#pragma unroll
  for (int i = 0; i < 4; i++)
#pragma unroll
    for (int j = 0; j < 4; j++) acc[i][j] = f32x4{0.f, 0.f, 0.f, 0.f};

  const int srow = lane >> 2;        // 0..15 row within 16-row chunk
  const int scol = (lane & 3) * 8;   // elem col offset (16B granules)

  for (int k0 = 0; k0 < K; k0 += 32) {
    __syncthreads();
#pragma unroll
    for (int cc = 0; cc < 2; cc++) {
      const int chunk = wid + cc * 4;  // 0..7
      gload_lds16(A + (size_t)(m0 + chunk * 16 + srow) * K + k0 + scol,
                  sA + chunk * 512);
      gload_lds16(BT + (size_t)(n0 + chunk * 16 + srow) * K + k0 + scol,
                  sB + chunk * 512);
    }
    __syncthreads();
    short8 af[4], bfr[4];
#pragma unroll
    for (int i = 0; i < 4; i++) {
      af[i] = *reinterpret_cast<const short8*>(
          sA + (wr * 64 + i * 16 + (lane & 15)) * 32 + (lane >> 4) * 8);
      bfr[i] = *reinterpret_cast<const short8*>(
          sB + (wc * 64 + i * 16 + (lane & 15)) * 32 + (lane >> 4) * 8);
    }
#pragma unroll
    for (int mi = 0; mi < 4; mi++)
#pragma unroll
      for (int ni = 0; ni < 4; ni++)
        acc[mi][ni] = __builtin_amdgcn_mfma_f32_16x16x32_bf16(
            af[mi], bfr[ni], acc[mi][ni], 0, 0, 0);
  }

#pragma unroll
  for (int ni = 0; ni < 4; ni++) {
    const int n = n0 + wc * 64 + ni * 16 + (lane & 15);
    const float bz = bias[n];
    const float sc = scale[n];
#pragma unroll
    for (int mi = 0; mi < 4; mi++) {
      const int mr = m0 + wr * 64 + mi * 16 + (lane >> 4) * 4;
#pragma unroll
      for (int j = 0; j < 4; j++) {
        float v = (acc[mi][ni][j] + bz) * sc;
        if (OUT_F32)
          reinterpret_cast<float*>(Cout)[(size_t)(mr + j) * N + n] = v;
        else
          reinterpret_cast<bf16*>(Cout)[(size_t)(mr + j) * N + n] = __float2bfloat16(v);
      }
    }
  }
}

// ------------------------------------- RoPE + head-reorder: (B,S,E) -> (B,H,S,D)
__global__ __launch_bounds__(256) void k_rope(const bf16* __restrict__ Y,
                                              const int* __restrict__ pos,
                                              bf16* __restrict__ Out, float mul) {
  const int idx = blockIdx.x * 256 + threadIdx.x;  // B*S*H*32 total pairs
  const int i = idx & 31;
  const int h = (idx >> 5) & 15;
  const int s = (idx >> 9) & 2047;
  const int b = idx >> 20;
  const float p = (float)pos[b * 2048 + s];
  const float ex = (float)(2 * i) * (1.0f / 64.0f);
  const float theta = 1.0f / powf(10000.0f, ex);
  const float ang = p * theta;
  float sn, cs;
  sincosf(ang, &sn, &cs);
  const size_t ybase = ((size_t)(b * 2048 + s)) * 1024 + h * 64 + 2 * i;
  ushort2 tv = *reinterpret_cast<const ushort2*>(Y + ybase);
  const float f0 = __uint_as_float(((unsigned)tv.x) << 16);
  const float f1 = __uint_as_float(((unsigned)tv.y) << 16);
  const float r0 = (f0 * cs - f1 * sn) * mul;
  const float r1 = (f0 * sn + f1 * cs) * mul;
  alignas(4) bf16 o2[2] = {__float2bfloat16(r0), __float2bfloat16(r1)};
  const size_t obase = (((size_t)(b * 16 + h)) * 2048 + s) * 64 + 2 * i;
  *reinterpret_cast<ushort2*>(Out + obase) = *reinterpret_cast<ushort2*>(o2);
}

// ------------------------------------- V transpose: (B,S,H,D) -> (B,H,D,S)
__global__ __launch_bounds__(256) void k_vtrans(const bf16* __restrict__ Yv,
                                                bf16* __restrict__ VT) {
  __shared__ bf16 tile[64][66];
  const int s0 = blockIdx.x * 64;
  const int bh = blockIdx.y;
  const int b = bh >> 4, h = bh & 15;
  const int r = threadIdx.x >> 6, c = threadIdx.x & 63;
#pragma unroll
  for (int i = 0; i < 16; i++)
    tile[r + i * 4][c] = Yv[(size_t)(b * 2048 + s0 + r + i * 4) * 1024 + h * 64 + c];
  __syncthreads();
#pragma unroll
  for (int i = 0; i < 16; i++)
    VT[((size_t)bh * 64 + r + i * 4) * 2048 + s0 + c] = tile[c][r + i * 4];
}

// ---------------------------------------------------------------- flash attention
// Q,K: (B*H, S, D) bf16 (Q pre-scaled by 1/8); VT: (B*H, D, S); Ctx out: (B,S,H,D)
__global__ __launch_bounds__(256) void k_attn(const bf16* __restrict__ Q,
                                              const bf16* __restrict__ Kt,
                                              const bf16* __restrict__ VT,
                                              bf16* __restrict__ Ctx) {
  __shared__ alignas(16) bf16 sK[64 * 64];   // [key][d], chunk-swizzled
  __shared__ alignas(16) bf16 sV[64 * 64];   // [d][key], chunk-swizzled
  __shared__ alignas(16) bf16 sP[4 * 16 * 72];

  const int lane = threadIdx.x & 63;
  const int wid = threadIdx.x >> 6;
  const int q0 = blockIdx.x * 64;
  const int bh = blockIdx.y;
  const int b = bh >> 4, h = bh & 15;

  // Q fragments (A operand), rows q0 + wid*16 + (lane&15)
  const bf16* Qbase = Q + ((size_t)bh * 2048 + q0 + wid * 16 + (lane & 15)) * 64;
  short8 qf[2];
  qf[0] = *reinterpret_cast<const short8*>(Qbase + (lane >> 4) * 8);
  qf[1] = *reinterpret_cast<const short8*>(Qbase + 32 + (lane >> 4) * 8);

  f32x4 accO[4];
#pragma unroll
  for (int i = 0; i < 4; i++) accO[i] = f32x4{0.f, 0.f, 0.f, 0.f};
  float mrow[4], lrow[4];
#pragma unroll
  for (int r = 0; r < 4; r++) { mrow[r] = -1e30f; lrow[r] = 0.f; }

  const int r8 = lane >> 3;   // staging row within 8-row chunk
  const int c8 = lane & 7;    // staging 16B-chunk within row
  const int gc = c8 ^ r8;     // pre-swizzled global chunk
  bf16* pw = sP + wid * 1152;

  for (int kt = 0; kt < 2048; kt += 64) {
    __syncthreads();
    // stage K tile [64 keys][64 d] and V tile [64 d][64 keys]
#pragma unroll
    for (int cc = 0; cc < 2; cc++) {
      const int chunk = wid + cc * 4;       // 0..7, 8 rows each
      const int row = chunk * 8 + r8;
      gload_lds16(Kt + ((size_t)bh * 2048 + kt + row) * 64 + gc * 8,
                  sK + chunk * 512);
      gload_lds16(VT + ((size_t)bh * 64 + row) * 2048 + kt + gc * 8,
                  sV + chunk * 512);
    }
    __syncthreads();

    // S = Q K^T (Q pre-scaled by 1/8)
    f32x4 accS[4];
#pragma unroll
    for (int i = 0; i < 4; i++) accS[i] = f32x4{0.f, 0.f, 0.f, 0.f};
#pragma unroll
    for (int ks = 0; ks < 2; ks++)
#pragma unroll
      for (int nf = 0; nf < 4; nf++) {
        const int krow = nf * 16 + (lane & 15);
        const int cq = ((lane >> 4) + 4 * ks) ^ (krow & 7);
        short8 kf = *reinterpret_cast<const short8*>(sK + krow * 64 + cq * 8);
        accS[nf] = __builtin_amdgcn_mfma_f32_16x16x32_bf16(qf[ks], kf, accS[nf], 0, 0, 0);
      }

    // online softmax (rows = (lane>>4)*4 + r, spread over 16 lanes of row group)
    float pv[4][4];
#pragma unroll
    for (int r = 0; r < 4; r++) {
      float mt = fmaxf(fmaxf(accS[0][r], accS[1][r]), fmaxf(accS[2][r], accS[3][r]));
#pragma unroll
      for (int off = 8; off >= 1; off >>= 1) mt = fmaxf(mt, __shfl_xor(mt, off));
      const float mn = fmaxf(mrow[r], mt);
      const float al = __expf(mrow[r] - mn);
      mrow[r] = mn;
      float s = 0.f;
#pragma unroll
      for (int nf = 0; nf < 4; nf++) {
        const float pp = __expf(accS[nf][r] - mn);
        pv[nf][r] = pp;
        s += pp;
      }
#pragma unroll
      for (int off = 8; off >= 1; off >>= 1) s += __shfl_xor(s, off);
      lrow[r] = lrow[r] * al + s;
#pragma unroll
      for (int nf = 0; nf < 4; nf++) accO[nf][r] *= al;
    }

    // P -> LDS (bf16), padded rows (72) to avoid bank conflicts
#pragma unroll
    for (int nf = 0; nf < 4; nf++)
#pragma unroll
      for (int r = 0; r < 4; r++)
        pw[((lane >> 4) * 4 + r) * 72 + nf * 16 + (lane & 15)] =
            __float2bfloat16(pv[nf][r]);
    __syncthreads();

    // O += P V
#pragma unroll
    for (int ks = 0; ks < 2; ks++) {
      short8 pa = *reinterpret_cast<const short8*>(
          pw + (lane & 15) * 72 + ((lane >> 4) + 4 * ks) * 8);
#pragma unroll
      for (int nf = 0; nf < 4; nf++) {
        const int d = nf * 16 + (lane & 15);
        const int cv = ((lane >> 4) + 4 * ks) ^ (d & 7);
        short8 vf = *reinterpret_cast<const short8*>(sV + d * 64 + cv * 8);
        accO[nf] = __builtin_amdgcn_mfma_f32_16x16x32_bf16(pa, vf, accO[nf], 0, 0, 0);
      }
    }
  }

  // write context (B,S,H,D)
#pragma unroll
  for (int nf = 0; nf < 4; nf++) {
    const int d = nf * 16 + (lane & 15);
#pragma unroll
    for (int r = 0; r < 4; r++) {
      const int q = q0 + wid * 16 + (lane >> 4) * 4 + r;
      const float o = accO[nf][r] / lrow[r];
      Ctx[(((size_t)b * 2048 + q) * 16 + h) * 64 + d] = __float2bfloat16(o);
    }
  }
}

// ================================================================ launch
// Workspace layout (72 MB total, lifetime-reused):
//   [ 0,16) MB  xb   (x in bf16)           -> reused as Qr after GEMM-V
//   [16,24) MB  WTq/WTk/WTv/WTo (2 MB each)
//   [24,40) MB  Yq                         -> reused as Kr after RoPE-Q
//   [40,56) MB  Yk                         -> reused as VT after RoPE-K
//   [56,72) MB  Yv                         -> reused as Ctx after V-trans
extern "C" void kernel_launch(void* const* d_in, const int* in_sizes, int n_in,
                              void* d_out, int out_size, void* d_ws, size_t ws_size,
                              hipStream_t stream) {
  const float* x = (const float*)d_in[0];
  const int* positions = (const int*)d_in[1];
  const float* Wq = (const float*)d_in[2];
  const float* bq = (const float*)d_in[3];
  const float* Wk = (const float*)d_in[4];
  const float* bk = (const float*)d_in[5];
  const float* Wv = (const float*)d_in[6];
  const float* bv = (const float*)d_in[7];
  const float* Wo = (const float*)d_in[8];
  const float* bo = (const float*)d_in[9];
  const float* q_scale = (const float*)d_in[10];
  const float* k_scale = (const float*)d_in[11];
  const float* v_scale = (const float*)d_in[12];
  const float* o_scale = (const float*)d_in[13];
  float* out = (float*)d_out;

  char* ws = (char*)d_ws;
  bf16* xb  = (bf16*)(ws);                 // 16 MB
  bf16* WTq = (bf16*)(ws + (16u << 20));   // 4 x 2 MB
  bf16* WTk = WTq + (1u << 20);
  bf16* WTv = WTk + (1u << 20);
  bf16* WTo = WTv + (1u << 20);
  bf16* Yq  = (bf16*)(ws + (24u << 20));
  bf16* Yk  = (bf16*)(ws + (40u << 20));
  bf16* Yv  = (bf16*)(ws + (56u << 20));
  bf16* Qr  = xb;   // xb dead after 3rd GEMM
  bf16* Kr  = Yq;   // Yq dead after RoPE-Q
  bf16* VT  = Yk;   // Yk dead after RoPE-K
  bf16* Ctx = Yv;   // Yv dead after V-transpose

  const int M = 8192, N = 1024, K = 1024;

  k_convert<<<8192, 256, 0, stream>>>(x, xb, M * K / 4);
  k_wtrans<<<dim3(16, 16, 4), 256, 0, stream>>>(Wq, Wk, Wv, Wo, WTq, WTk, WTv, WTo);

  k_gemm_bt<0><<<dim3(64, 8), 256, 0, stream>>>(xb, WTq, bq, q_scale, Yq, M, N, K);
  k_gemm_bt<0><<<dim3(64, 8), 256, 0, stream>>>(xb, WTk, bk, k_scale, Yk, M, N, K);
  k_gemm_bt<0><<<dim3(64, 8), 256, 0, stream>>>(xb, WTv, bv, v_scale, Yv, M, N, K);

  k_rope<<<16384, 256, 0, stream>>>(Yq, positions, Qr, 0.125f);  // fold 1/sqrt(D)
  k_rope<<<16384, 256, 0, stream>>>(Yk, positions, Kr, 1.0f);
  k_vtrans<<<dim3(32, 64), 256, 0, stream>>>(Yv, VT);

  k_attn<<<dim3(32, 64), 256, 0, stream>>>(Qr, Kr, VT, Ctx);

  k_gemm_bt<1><<<dim3(64, 8), 256, 0, stream>>>(Ctx, WTo, bo, o_scale, out, M, N, K);
}

// Round 4
// 399.466 us; speedup vs baseline: 1.2372x; 1.2372x over previous
//
#include <hip/hip_runtime.h>
#include <hip/hip_bf16.h>

using bf16 = __hip_bfloat16;
typedef __attribute__((ext_vector_type(8))) short short8;
typedef __attribute__((ext_vector_type(4))) float f32x4;
typedef __attribute__((ext_vector_type(16))) float f32x16;

#define AS1 __attribute__((address_space(1)))
#define AS3 __attribute__((address_space(3)))

__device__ __forceinline__ void gload_lds16(const void* g, void* l) {
  __builtin_amdgcn_global_load_lds((const AS1 unsigned int*)g,
                                   (AS3 unsigned int*)l, 16, 0, 0);
}

__device__ __forceinline__ unsigned cvtpk_bf16(float lo, float hi) {
  unsigned r;
  asm("v_cvt_pk_bf16_f32 %0, %1, %2" : "=v"(r) : "v"(lo), "v"(hi));
  return r;
}

// v_permlane32_swap_b32: a.hi32lanes <-> b.lo32lanes
__device__ __forceinline__ void pl32swap(unsigned &a, unsigned &b) {
  asm("v_permlane32_swap_b32 %0, %1" : "+v"(a), "+v"(b));
}

// ---------------------------------------------------------------- convert f32 -> bf16
__global__ __launch_bounds__(256) void k_convert(const float* __restrict__ src,
                                                 bf16* __restrict__ dst, int n4) {
  int i = blockIdx.x * 256 + threadIdx.x;
  if (i >= n4) return;
  float4 v = reinterpret_cast<const float4*>(src)[i];
  alignas(8) bf16 o[4] = {__float2bfloat16(v.x), __float2bfloat16(v.y),
                          __float2bfloat16(v.z), __float2bfloat16(v.w)};
  *reinterpret_cast<uint2*>(dst + (size_t)i * 4) = *reinterpret_cast<uint2*>(o);
}

// ------------------------------------------- transpose+convert W (k,n) -> WT bf16 (n,k)
__global__ __launch_bounds__(256) void k_wtrans(
    const float* __restrict__ W0, const float* __restrict__ W1,
    const float* __restrict__ W2, const float* __restrict__ W3,
    bf16* __restrict__ T0, bf16* __restrict__ T1,
    bf16* __restrict__ T2, bf16* __restrict__ T3) {
  __shared__ float tile[64][65];
  const float* W; bf16* T;
  switch (blockIdx.z) {
    case 0: W = W0; T = T0; break;
    case 1: W = W1; T = T1; break;
    case 2: W = W2; T = T2; break;
    default: W = W3; T = T3; break;
  }
  const int k0 = blockIdx.x * 64, n0 = blockIdx.y * 64;
  const int r = threadIdx.x >> 6, c = threadIdx.x & 63;
#pragma unroll
  for (int i = 0; i < 16; i++)
    tile[r + i * 4][c] = W[(size_t)(k0 + r + i * 4) * 1024 + n0 + c];
  __syncthreads();
#pragma unroll
  for (int i = 0; i < 16; i++)
    T[(size_t)(n0 + r + i * 4) * 1024 + k0 + c] = __float2bfloat16(tile[c][r + i * 4]);
}

// ---------------------------------------------------------------- GEMM: C = A @ BT^T
template <int OUT_F32>
__global__ __launch_bounds__(256) void k_gemm_bt(
    const bf16* __restrict__ A, const bf16* __restrict__ BT,
    const float* __restrict__ bias, const float* __restrict__ scale,
    void* __restrict__ Cout, int M, int N, int K) {
  __shared__ alignas(16) bf16 sA[128 * 32];
  __shared__ alignas(16) bf16 sB[128 * 32];
  const int lane = threadIdx.x & 63;
  const int wid = threadIdx.x >> 6;
  const int wr = wid >> 1, wc = wid & 1;
  const int m0 = blockIdx.x * 128;
  const int n0 = blockIdx.y * 128;

  f32x4 acc[4][4];
#pragma unroll
  for (int i = 0; i < 4; i++)
#pragma unroll
    for (int j = 0; j < 4; j++) acc[i][j] = f32x4{0.f, 0.f, 0.f, 0.f};

  const int srow = lane >> 2;
  const int scol = (lane & 3) * 8;

  for (int k0 = 0; k0 < K; k0 += 32) {
    __syncthreads();
#pragma unroll
    for (int cc = 0; cc < 2; cc++) {
      const int chunk = wid + cc * 4;
      gload_lds16(A + (size_t)(m0 + chunk * 16 + srow) * K + k0 + scol,
                  sA + chunk * 512);
      gload_lds16(BT + (size_t)(n0 + chunk * 16 + srow) * K + k0 + scol,
                  sB + chunk * 512);
    }
    __syncthreads();
    short8 af[4], bfr[4];
#pragma unroll
    for (int i = 0; i < 4; i++) {
      af[i] = *reinterpret_cast<const short8*>(
          sA + (wr * 64 + i * 16 + (lane & 15)) * 32 + (lane >> 4) * 8);
      bfr[i] = *reinterpret_cast<const short8*>(
          sB + (wc * 64 + i * 16 + (lane & 15)) * 32 + (lane >> 4) * 8);
    }
#pragma unroll
    for (int mi = 0; mi < 4; mi++)
#pragma unroll
      for (int ni = 0; ni < 4; ni++)
        acc[mi][ni] = __builtin_amdgcn_mfma_f32_16x16x32_bf16(
            af[mi], bfr[ni], acc[mi][ni], 0, 0, 0);
  }

#pragma unroll
  for (int ni = 0; ni < 4; ni++) {
    const int n = n0 + wc * 64 + ni * 16 + (lane & 15);
    const float bz = bias[n];
    const float sc = scale[n];
#pragma unroll
    for (int mi = 0; mi < 4; mi++) {
      const int mr = m0 + wr * 64 + mi * 16 + (lane >> 4) * 4;
#pragma unroll
      for (int j = 0; j < 4; j++) {
        float v = (acc[mi][ni][j] + bz) * sc;
        if (OUT_F32)
          reinterpret_cast<float*>(Cout)[(size_t)(mr + j) * N + n] = v;
        else
          reinterpret_cast<bf16*>(Cout)[(size_t)(mr + j) * N + n] = __float2bfloat16(v);
      }
    }
  }
}

// ------------------------------------- RoPE + head-reorder: (B,S,E) -> (B,H,S,D)
__global__ __launch_bounds__(256) void k_rope(const bf16* __restrict__ Y,
                                              const int* __restrict__ pos,
                                              bf16* __restrict__ Out, float mul) {
  const int idx = blockIdx.x * 256 + threadIdx.x;
  const int i = idx & 31;
  const int h = (idx >> 5) & 15;
  const int s = (idx >> 9) & 2047;
  const int b = idx >> 20;
  const float p = (float)pos[b * 2048 + s];
  const float ex = (float)(2 * i) * (1.0f / 64.0f);
  const float theta = 1.0f / powf(10000.0f, ex);
  const float ang = p * theta;
  float sn, cs;
  sincosf(ang, &sn, &cs);
  const size_t ybase = ((size_t)(b * 2048 + s)) * 1024 + h * 64 + 2 * i;
  ushort2 tv = *reinterpret_cast<const ushort2*>(Y + ybase);
  const float f0 = __uint_as_float(((unsigned)tv.x) << 16);
  const float f1 = __uint_as_float(((unsigned)tv.y) << 16);
  const float r0 = (f0 * cs - f1 * sn) * mul;
  const float r1 = (f0 * sn + f1 * cs) * mul;
  alignas(4) bf16 o2[2] = {__float2bfloat16(r0), __float2bfloat16(r1)};
  const size_t obase = (((size_t)(b * 16 + h)) * 2048 + s) * 64 + 2 * i;
  *reinterpret_cast<ushort2*>(Out + obase) = *reinterpret_cast<ushort2*>(o2);
}

// ------------------------------------- V transpose: (B,S,H,D) -> (B,H,D,S)
__global__ __launch_bounds__(256) void k_vtrans(const bf16* __restrict__ Yv,
                                                bf16* __restrict__ VT) {
  __shared__ bf16 tile[64][66];
  const int s0 = blockIdx.x * 64;
  const int bh = blockIdx.y;
  const int b = bh >> 4, h = bh & 15;
  const int r = threadIdx.x >> 6, c = threadIdx.x & 63;
#pragma unroll
  for (int i = 0; i < 16; i++)
    tile[r + i * 4][c] = Yv[(size_t)(b * 2048 + s0 + r + i * 4) * 1024 + h * 64 + c];
  __syncthreads();
#pragma unroll
  for (int i = 0; i < 16; i++)
    VT[((size_t)bh * 64 + r + i * 4) * 2048 + s0 + c] = tile[c][r + i * 4];
}

// ---------------------------------------------------------------- flash attention
// Swapped-operand 32x32x16 structure: per warp 32 q-rows, KVBLK=64.
// Q pre-scaled by (1/8)*log2(e) so P = exp2(S - m). Softmax fully in-register
// (lane owns q=lane&31; cross-half exchange via shfl_xor 32). P->bf16 A-frags
// via v_cvt_pk_bf16_f32 + v_permlane32_swap_b32 (no LDS round-trip).
// PV computes O^T = V^T x P so rescale/divide stay lane-local.
// Q,K: (B*H,S,D) bf16; VT: (B*H,D,S); Ctx out: (B,S,H,D)
__global__ __launch_bounds__(256, 2) void k_attn(const bf16* __restrict__ Q,
                                                 const bf16* __restrict__ Kt,
                                                 const bf16* __restrict__ VT,
                                                 bf16* __restrict__ Ctx) {
  __shared__ alignas(16) bf16 sK[2][64 * 64];  // dbuf [key][d], chunk-swizzled
  __shared__ alignas(16) bf16 sV[2][64 * 64];  // dbuf [d][key], chunk-swizzled

  const int lane = threadIdx.x & 63;
  const int w = threadIdx.x >> 6;     // 4 warps x 32 q-rows
  const int q0 = blockIdx.x * 128;
  const int bh = blockIdx.y;
  const int b = bh >> 4, h = bh & 15;
  const int ql = lane & 31;           // q within warp tile (output col)
  const int hi = lane >> 5;
  const int r8 = lane >> 3;           // staging row within 8-row chunk
  const int gslot = (lane & 7) ^ r8;  // pre-swizzled global 16B slot

  // Q fragments (B-operand): qf[ks] = Q[q][16*ks + 8*hi + j]
  const bf16* Qrow = Q + ((size_t)bh * 2048 + q0 + w * 32 + ql) * 64;
  short8 qf[4];
#pragma unroll
  for (int ks = 0; ks < 4; ks++)
    qf[ks] = *reinterpret_cast<const short8*>(Qrow + ks * 16 + hi * 8);

  f32x16 accO[2];
#pragma unroll
  for (int dt = 0; dt < 2; dt++)
#pragma unroll
    for (int r = 0; r < 16; r++) accO[dt][r] = 0.f;
  float m = -1e30f, l = 0.f;

  const size_t kbase = (size_t)bh * 2048 * 64;
  const size_t vbase = (size_t)bh * 64 * 2048;

  // prologue: stage tile 0
#pragma unroll
  for (int cc = 0; cc < 2; cc++) {
    const int ch = w + cc * 4, row = ch * 8 + r8;
    gload_lds16(Kt + kbase + (size_t)row * 64 + gslot * 8, &sK[0][ch * 512]);
    gload_lds16(VT + vbase + (size_t)row * 2048 + gslot * 8, &sV[0][ch * 512]);
  }

  for (int it = 0; it < 32; ++it) {
    __syncthreads();  // drains stage(it) [issued last iter], guards buffers
    const int cur = it & 1;
    if (it + 1 < 32) {  // stage(it+1): latency hides under compute(it)
      const int nxt = cur ^ 1, kt = (it + 1) * 64;
#pragma unroll
      for (int cc = 0; cc < 2; cc++) {
        const int ch = w + cc * 4, row = ch * 8 + r8;
        gload_lds16(Kt + kbase + (size_t)(kt + row) * 64 + gslot * 8,
                    &sK[nxt][ch * 512]);
        gload_lds16(VT + vbase + (size_t)row * 2048 + kt + gslot * 8,
                    &sV[nxt][ch * 512]);
      }
    }

    // QK^T swapped: accS[t][reg] = S^T[k=32t+crow(reg,hi)][q=ql]
    f32x16 accS[2];
#pragma unroll
    for (int t = 0; t < 2; t++) {
#pragma unroll
      for (int r = 0; r < 16; r++) accS[t][r] = 0.f;
#pragma unroll
      for (int ks = 0; ks < 4; ks++) {
        const int row = 32 * t + ql;
        const int cs = (2 * ks + hi) ^ (lane & 7);
        short8 kf = *reinterpret_cast<const short8*>(&sK[cur][row * 64 + cs * 8]);
        accS[t] =
            __builtin_amdgcn_mfma_f32_32x32x16_bf16(kf, qf[ks], accS[t], 0, 0, 0);
      }
    }

    // in-register online softmax (log2 units)
    float pmax = -1e30f;
#pragma unroll
    for (int t = 0; t < 2; t++)
#pragma unroll
      for (int r = 0; r < 16; r++) pmax = fmaxf(pmax, accS[t][r]);
    pmax = fmaxf(pmax, __shfl_xor(pmax, 32, 64));
    if (__any(pmax - m > 11.0f)) {  // defer-max: skip rescale when growth small
      const float mn = fmaxf(m, pmax);
      const float al = exp2f(m - mn);
      m = mn;
      l *= al;
#pragma unroll
      for (int dt = 0; dt < 2; dt++)
#pragma unroll
        for (int r = 0; r < 16; r++) accO[dt][r] *= al;
    }
    float s = 0.f;
#pragma unroll
    for (int t = 0; t < 2; t++)
#pragma unroll
      for (int r = 0; r < 16; r++) {
        const float p = exp2f(accS[t][r] - m);
        accS[t][r] = p;
        s += p;
      }
    s += __shfl_xor(s, 32, 64);
    l += s;

    // PV: accO[dt] += V^T x P, k-steps of 16
#pragma unroll
    for (int ss = 0; ss < 4; ss++) {
      const int t = ss >> 1, base = (ss & 1) * 8;
      unsigned w01 = cvtpk_bf16(accS[t][base + 0], accS[t][base + 1]);
      unsigned w23 = cvtpk_bf16(accS[t][base + 2], accS[t][base + 3]);
      unsigned w45 = cvtpk_bf16(accS[t][base + 4], accS[t][base + 5]);
      unsigned w67 = cvtpk_bf16(accS[t][base + 6], accS[t][base + 7]);
      pl32swap(w01, w45);  // -> j={0,1} / {4,5}, k = 8*hi + j
      pl32swap(w23, w67);  // -> j={2,3} / {6,7}
      uint4 pau = {w01, w23, w45, w67};
      short8 pa = *reinterpret_cast<short8*>(&pau);
#pragma unroll
      for (int dt = 0; dt < 2; dt++) {
        const int row = 32 * dt + ql;
        const int cs = (2 * ss + hi) ^ (lane & 7);
        short8 vf = *reinterpret_cast<const short8*>(&sV[cur][row * 64 + cs * 8]);
        accO[dt] =
            __builtin_amdgcn_mfma_f32_32x32x16_bf16(vf, pa, accO[dt], 0, 0, 0);
      }
    }
  }

  // epilogue: O^T regs -> LDS transpose (swizzled) -> coalesced global
  __syncthreads();
  bf16* tw = &sK[0][0] + w * 2048;  // 4KB per warp
  const float inv = 1.0f / l;
#pragma unroll
  for (int dt = 0; dt < 2; dt++)
#pragma unroll
    for (int g = 0; g < 4; g++) {
      unsigned wa = cvtpk_bf16(accO[dt][4 * g + 0] * inv, accO[dt][4 * g + 1] * inv);
      unsigned wb = cvtpk_bf16(accO[dt][4 * g + 2] * inv, accO[dt][4 * g + 3] * inv);
      const int c = (4 * dt + g) ^ (ql & 7);
      uint2 val = {wa, wb};
      *reinterpret_cast<uint2*>(tw + ql * 64 + c * 8 + hi * 4) = val;
    }
  __syncthreads();
  const int qr = lane >> 1, half = lane & 1;
  const size_t orow = (((size_t)b * 2048 + q0 + w * 32 + qr) * 16 + h) * 64;
#pragma unroll
  for (int i = 0; i < 4; i++) {
    const int c2 = (half * 4 + i) ^ (qr & 7);
    short8 v = *reinterpret_cast<const short8*>(tw + qr * 64 + c2 * 8);
    *reinterpret_cast<short8*>(Ctx + orow + half * 32 + i * 8) = v;
  }
}

// ================================================================ launch
// Workspace layout (72 MB total, lifetime-reused):
//   [ 0,16) MB  xb   (x in bf16)           -> reused as Qr after GEMM-V
//   [16,24) MB  WTq/WTk/WTv/WTo (2 MB each)
//   [24,40) MB  Yq                         -> reused as Kr after RoPE-Q
//   [40,56) MB  Yk                         -> reused as VT after RoPE-K
//   [56,72) MB  Yv                         -> reused as Ctx after V-trans
extern "C" void kernel_launch(void* const* d_in, const int* in_sizes, int n_in,
                              void* d_out, int out_size, void* d_ws, size_t ws_size,
                              hipStream_t stream) {
  const float* x = (const float*)d_in[0];
  const int* positions = (const int*)d_in[1];
  const float* Wq = (const float*)d_in[2];
  const float* bq = (const float*)d_in[3];
  const float* Wk = (const float*)d_in[4];
  const float* bk = (const float*)d_in[5];
  const float* Wv = (const float*)d_in[6];
  const float* bv = (const float*)d_in[7];
  const float* Wo = (const float*)d_in[8];
  const float* bo = (const float*)d_in[9];
  const float* q_scale = (const float*)d_in[10];
  const float* k_scale = (const float*)d_in[11];
  const float* v_scale = (const float*)d_in[12];
  const float* o_scale = (const float*)d_in[13];
  float* out = (float*)d_out;

  char* ws = (char*)d_ws;
  bf16* xb  = (bf16*)(ws);                 // 16 MB
  bf16* WTq = (bf16*)(ws + (16u << 20));   // 4 x 2 MB
  bf16* WTk = WTq + (1u << 20);
  bf16* WTv = WTk + (1u << 20);
  bf16* WTo = WTv + (1u << 20);
  bf16* Yq  = (bf16*)(ws + (24u << 20));
  bf16* Yk  = (bf16*)(ws + (40u << 20));
  bf16* Yv  = (bf16*)(ws + (56u << 20));
  bf16* Qr  = xb;   // xb dead after 3rd GEMM
  bf16* Kr  = Yq;   // Yq dead after RoPE-Q
  bf16* VT  = Yk;   // Yk dead after RoPE-K
  bf16* Ctx = Yv;   // Yv dead after V-transpose

  const int M = 8192, N = 1024, K = 1024;

  k_convert<<<8192, 256, 0, stream>>>(x, xb, M * K / 4);
  k_wtrans<<<dim3(16, 16, 4), 256, 0, stream>>>(Wq, Wk, Wv, Wo, WTq, WTk, WTv, WTo);

  k_gemm_bt<0><<<dim3(64, 8), 256, 0, stream>>>(xb, WTq, bq, q_scale, Yq, M, N, K);
  k_gemm_bt<0><<<dim3(64, 8), 256, 0, stream>>>(xb, WTk, bk, k_scale, Yk, M, N, K);
  k_gemm_bt<0><<<dim3(64, 8), 256, 0, stream>>>(xb, WTv, bv, v_scale, Yv, M, N, K);

  // Q pre-scale: (1/sqrt(64)) * log2(e) so attention uses exp2 directly
  k_rope<<<16384, 256, 0, stream>>>(Yq, positions, Qr, 0.18033688011112042f);
  k_rope<<<16384, 256, 0, stream>>>(Yk, positions, Kr, 1.0f);
  k_vtrans<<<dim3(32, 64), 256, 0, stream>>>(Yv, VT);

  k_attn<<<dim3(16, 64), 256, 0, stream>>>(Qr, Kr, VT, Ctx);

  k_gemm_bt<1><<<dim3(64, 8), 256, 0, stream>>>(Ctx, WTo, bo, o_scale, out, M, N, K);
}

// Round 5
// 378.943 us; speedup vs baseline: 1.3042x; 1.0542x over previous
//
#include <hip/hip_runtime.h>
#include <hip/hip_bf16.h>

using bf16 = __hip_bfloat16;
typedef __attribute__((ext_vector_type(8))) short short8;
typedef __attribute__((ext_vector_type(4))) float f32x4;
typedef __attribute__((ext_vector_type(16))) float f32x16;

#define AS1 __attribute__((address_space(1)))
#define AS3 __attribute__((address_space(3)))

__device__ __forceinline__ void gload_lds16(const void* g, void* l) {
  __builtin_amdgcn_global_load_lds((const AS1 unsigned int*)g,
                                   (AS3 unsigned int*)l, 16, 0, 0);
}

__device__ __forceinline__ unsigned cvtpk_bf16(float lo, float hi) {
  unsigned r;
  asm("v_cvt_pk_bf16_f32 %0, %1, %2" : "=v"(r) : "v"(lo), "v"(hi));
  return r;
}

// v_permlane32_swap_b32: a.hi32lanes <-> b.lo32lanes
__device__ __forceinline__ void pl32swap(unsigned &a, unsigned &b) {
  asm("v_permlane32_swap_b32 %0, %1" : "+v"(a), "+v"(b));
}

__device__ __forceinline__ float fm3(float a, float b, float c) {
  return fmaxf(fmaxf(a, b), c);  // clang fuses to v_max3_f32
}

// ---------------------------------------------------------------- convert f32 -> bf16
__global__ __launch_bounds__(256) void k_convert(const float* __restrict__ src,
                                                 bf16* __restrict__ dst, int n4) {
  int i = blockIdx.x * 256 + threadIdx.x;
  if (i >= n4) return;
  float4 v = reinterpret_cast<const float4*>(src)[i];
  alignas(8) bf16 o[4] = {__float2bfloat16(v.x), __float2bfloat16(v.y),
                          __float2bfloat16(v.z), __float2bfloat16(v.w)};
  *reinterpret_cast<uint2*>(dst + (size_t)i * 4) = *reinterpret_cast<uint2*>(o);
}

// ------------------------------------------- transpose+convert W (k,n) -> WT bf16 (n,k)
__global__ __launch_bounds__(256) void k_wtrans(
    const float* __restrict__ W0, const float* __restrict__ W1,
    const float* __restrict__ W2, const float* __restrict__ W3,
    bf16* __restrict__ T0, bf16* __restrict__ T1,
    bf16* __restrict__ T2, bf16* __restrict__ T3) {
  __shared__ float tile[64][65];
  const float* W; bf16* T;
  switch (blockIdx.z) {
    case 0: W = W0; T = T0; break;
    case 1: W = W1; T = T1; break;
    case 2: W = W2; T = T2; break;
    default: W = W3; T = T3; break;
  }
  const int k0 = blockIdx.x * 64, n0 = blockIdx.y * 64;
  const int r = threadIdx.x >> 6, c = threadIdx.x & 63;
#pragma unroll
  for (int i = 0; i < 16; i++)
    tile[r + i * 4][c] = W[(size_t)(k0 + r + i * 4) * 1024 + n0 + c];
  __syncthreads();
#pragma unroll
  for (int i = 0; i < 16; i++)
    T[(size_t)(n0 + r + i * 4) * 1024 + k0 + c] = __float2bfloat16(tile[c][r + i * 4]);
}

// ------------------------------------------------- fused QKV GEMM: Y_seg = x @ WT_seg^T
// A: 8192x1024 bf16; BT: 3072x1024 bf16 (WTq|WTk|WTv contiguous). 128x128 tile, BK=32.
// Block column n0 selects segment (0:Q 1:K 2:V); dst buffers spaced 8M elems.
__global__ __launch_bounds__(256) void k_gemm_qkv(
    const bf16* __restrict__ A, const bf16* __restrict__ BT,
    const float* __restrict__ bq, const float* __restrict__ bk,
    const float* __restrict__ bv, const float* __restrict__ sq,
    const float* __restrict__ sk, const float* __restrict__ sv,
    bf16* __restrict__ Yqkv) {
  __shared__ alignas(16) bf16 sA[128 * 32];
  __shared__ alignas(16) bf16 sB[128 * 32];
  const int K = 1024;
  const int lane = threadIdx.x & 63;
  const int wid = threadIdx.x >> 6;
  const int wr = wid >> 1, wc = wid & 1;
  const int m0 = blockIdx.x * 128;
  const int n0 = blockIdx.y * 128;

  f32x4 acc[4][4];
#pragma unroll
  for (int i = 0; i < 4; i++)
#pragma unroll
    for (int j = 0; j < 4; j++) acc[i][j] = f32x4{0.f, 0.f, 0.f, 0.f};

  const int srow = lane >> 2;
  const int scol = (lane & 3) * 8;

  for (int k0 = 0; k0 < K; k0 += 32) {
    __syncthreads();
#pragma unroll
    for (int cc = 0; cc < 2; cc++) {
      const int chunk = wid + cc * 4;
      gload_lds16(A + (size_t)(m0 + chunk * 16 + srow) * K + k0 + scol,
                  sA + chunk * 512);
      gload_lds16(BT + (size_t)(n0 + chunk * 16 + srow) * K + k0 + scol,
                  sB + chunk * 512);
    }
    __syncthreads();
    short8 af[4], bfr[4];
#pragma unroll
    for (int i = 0; i < 4; i++) {
      af[i] = *reinterpret_cast<const short8*>(
          sA + (wr * 64 + i * 16 + (lane & 15)) * 32 + (lane >> 4) * 8);
      bfr[i] = *reinterpret_cast<const short8*>(
          sB + (wc * 64 + i * 16 + (lane & 15)) * 32 + (lane >> 4) * 8);
    }
#pragma unroll
    for (int mi = 0; mi < 4; mi++)
#pragma unroll
      for (int ni = 0; ni < 4; ni++)
        acc[mi][ni] = __builtin_amdgcn_mfma_f32_16x16x32_bf16(
            af[mi], bfr[ni], acc[mi][ni], 0, 0, 0);
  }

  const int seg = n0 >> 10;
  bf16* dst = Yqkv + (size_t)seg * (8u << 20);
  const float* bias = seg == 0 ? bq : (seg == 1 ? bk : bv);
  const float* scale = seg == 0 ? sq : (seg == 1 ? sk : sv);
  const int nb = n0 & 1023;
#pragma unroll
  for (int ni = 0; ni < 4; ni++) {
    const int n = nb + wc * 64 + ni * 16 + (lane & 15);
    const float bz = bias[n];
    const float sc = scale[n];
#pragma unroll
    for (int mi = 0; mi < 4; mi++) {
      const int mr = m0 + wr * 64 + mi * 16 + (lane >> 4) * 4;
#pragma unroll
      for (int j = 0; j < 4; j++)
        dst[(size_t)(mr + j) * 1024 + n] = __float2bfloat16((acc[mi][ni][j] + bz) * sc);
    }
  }
}

// ---------------------------------------------------------------- O-proj GEMM (f32 out)
__global__ __launch_bounds__(256) void k_gemm_bt(
    const bf16* __restrict__ A, const bf16* __restrict__ BT,
    const float* __restrict__ bias, const float* __restrict__ scale,
    float* __restrict__ Cout, int M, int N, int K) {
  __shared__ alignas(16) bf16 sA[128 * 32];
  __shared__ alignas(16) bf16 sB[128 * 32];
  const int lane = threadIdx.x & 63;
  const int wid = threadIdx.x >> 6;
  const int wr = wid >> 1, wc = wid & 1;
  const int m0 = blockIdx.x * 128;
  const int n0 = blockIdx.y * 128;

  f32x4 acc[4][4];
#pragma unroll
  for (int i = 0; i < 4; i++)
#pragma unroll
    for (int j = 0; j < 4; j++) acc[i][j] = f32x4{0.f, 0.f, 0.f, 0.f};

  const int srow = lane >> 2;
  const int scol = (lane & 3) * 8;

  for (int k0 = 0; k0 < K; k0 += 32) {
    __syncthreads();
#pragma unroll
    for (int cc = 0; cc < 2; cc++) {
      const int chunk = wid + cc * 4;
      gload_lds16(A + (size_t)(m0 + chunk * 16 + srow) * K + k0 + scol,
                  sA + chunk * 512);
      gload_lds16(BT + (size_t)(n0 + chunk * 16 + srow) * K + k0 + scol,
                  sB + chunk * 512);
    }
    __syncthreads();
    short8 af[4], bfr[4];
#pragma unroll
    for (int i = 0; i < 4; i++) {
      af[i] = *reinterpret_cast<const short8*>(
          sA + (wr * 64 + i * 16 + (lane & 15)) * 32 + (lane >> 4) * 8);
      bfr[i] = *reinterpret_cast<const short8*>(
          sB + (wc * 64 + i * 16 + (lane & 15)) * 32 + (lane >> 4) * 8);
    }
#pragma unroll
    for (int mi = 0; mi < 4; mi++)
#pragma unroll
      for (int ni = 0; ni < 4; ni++)
        acc[mi][ni] = __builtin_amdgcn_mfma_f32_16x16x32_bf16(
            af[mi], bfr[ni], acc[mi][ni], 0, 0, 0);
  }

#pragma unroll
  for (int ni = 0; ni < 4; ni++) {
    const int n = n0 + wc * 64 + ni * 16 + (lane & 15);
    const float bz = bias[n];
    const float sc = scale[n];
#pragma unroll
    for (int mi = 0; mi < 4; mi++) {
      const int mr = m0 + wr * 64 + mi * 16 + (lane >> 4) * 4;
#pragma unroll
      for (int j = 0; j < 4; j++)
        Cout[(size_t)(mr + j) * N + n] = (acc[mi][ni][j] + bz) * sc;
    }
  }
}

// ------------------------------------- RoPE + head-reorder: (B,S,E) -> (B,H,S,D)
// Vectorized: each thread handles 16 bf16 (8 rotation pairs, 32B loads/stores).
// Per-element math identical to the scalar version (powf + sincosf).
__global__ __launch_bounds__(256) void k_rope(const bf16* __restrict__ Y,
                                              const int* __restrict__ pos,
                                              bf16* __restrict__ Out, float mul) {
  const int idx = blockIdx.x * 256 + threadIdx.x;  // 524288 total
  const int c = idx & 3;
  const int h = (idx >> 2) & 15;
  const int s = (idx >> 6) & 2047;
  const int b = idx >> 17;
  const float p = (float)pos[b * 2048 + s];
  const size_t ybase = ((size_t)(b * 2048 + s)) * 1024 + h * 64 + c * 16;
  const size_t obase = (((size_t)(b * 16 + h)) * 2048 + s) * 64 + c * 16;

  union { short8 v[2]; short a[16]; } in, out;
  in.v[0] = *reinterpret_cast<const short8*>(Y + ybase);
  in.v[1] = *reinterpret_cast<const short8*>(Y + ybase + 8);
#pragma unroll
  for (int j = 0; j < 8; j++) {
    const int i = c * 8 + j;  // pair index 0..31
    const float ex = (float)(2 * i) * (1.0f / 64.0f);
    const float theta = 1.0f / powf(10000.0f, ex);
    float sn, cs;
    sincosf(p * theta, &sn, &cs);
    const float f0 = __uint_as_float(((unsigned)(unsigned short)in.a[2 * j]) << 16);
    const float f1 = __uint_as_float(((unsigned)(unsigned short)in.a[2 * j + 1]) << 16);
    out.a[2 * j] = (short)__bfloat16_as_ushort(__float2bfloat16((f0 * cs - f1 * sn) * mul));
    out.a[2 * j + 1] = (short)__bfloat16_as_ushort(__float2bfloat16((f0 * sn + f1 * cs) * mul));
  }
  *reinterpret_cast<short8*>(Out + obase) = out.v[0];
  *reinterpret_cast<short8*>(Out + obase + 8) = out.v[1];
}

// ------------------------------------- V transpose: (B,S,H,D) -> (B,H,D,S)
__global__ __launch_bounds__(256) void k_vtrans(const bf16* __restrict__ Yv,
                                                bf16* __restrict__ VT) {
  __shared__ bf16 tile[64][66];
  const int s0 = blockIdx.x * 64;
  const int bh = blockIdx.y;
  const int b = bh >> 4, h = bh & 15;
  const int r = threadIdx.x >> 6, c = threadIdx.x & 63;
#pragma unroll
  for (int i = 0; i < 16; i++)
    tile[r + i * 4][c] = Yv[(size_t)(b * 2048 + s0 + r + i * 4) * 1024 + h * 64 + c];
  __syncthreads();
#pragma unroll
  for (int i = 0; i < 16; i++)
    VT[((size_t)bh * 64 + r + i * 4) * 2048 + s0 + c] = tile[c][r + i * 4];
}

// ---------------------------------------------------------------- flash attention
// Swapped-operand 32x32x16; 8 warps x 32 q-rows = QBLK 256; KVBLK=64 double-buffered.
// Q pre-scaled by (1/8)*log2(e) so P = exp2(S - m). Softmax fully in-register.
// P->bf16 A-frags via v_cvt_pk_bf16_f32 + v_permlane32_swap_b32.
// PV computes O^T = V^T x P so rescale/divide stay lane-local.
__global__ __launch_bounds__(512, 4) void k_attn(const bf16* __restrict__ Q,
                                                 const bf16* __restrict__ Kt,
                                                 const bf16* __restrict__ VT,
                                                 bf16* __restrict__ Ctx) {
  __shared__ alignas(16) bf16 smem[4][4096];  // [0],[1]=K dbuf; [2],[3]=V dbuf

  const int lane = threadIdx.x & 63;
  const int w = threadIdx.x >> 6;     // 8 warps x 32 q-rows
  const int q0 = blockIdx.x * 256;
  const int bh = blockIdx.y;
  const int b = bh >> 4, h = bh & 15;
  const int ql = lane & 31;           // q within warp tile (output col)
  const int hi = lane >> 5;
  const int r8 = lane >> 3;           // staging row within 8-row chunk
  const int gslot = (lane & 7) ^ r8;  // pre-swizzled global 16B slot
  const int row_st = w * 8 + r8;      // staging row 0..63 (warp w owns chunk w)

  // Q fragments (B-operand): qf[ks] = Q[q][16*ks + 8*hi + j]
  const bf16* Qrow = Q + ((size_t)bh * 2048 + q0 + w * 32 + ql) * 64;
  short8 qf[4];
#pragma unroll
  for (int ks = 0; ks < 4; ks++)
    qf[ks] = *reinterpret_cast<const short8*>(Qrow + ks * 16 + hi * 8);

  f32x16 accO[2];
#pragma unroll
  for (int dt = 0; dt < 2; dt++)
#pragma unroll
    for (int r = 0; r < 16; r++) accO[dt][r] = 0.f;
  float m = -1e30f, l = 0.f;

  const size_t kbase = (size_t)bh * 2048 * 64;
  const size_t vbase = (size_t)bh * 64 * 2048;

  // prologue: stage tile 0
  gload_lds16(Kt + kbase + (size_t)row_st * 64 + gslot * 8, &smem[0][w * 512]);
  gload_lds16(VT + vbase + (size_t)row_st * 2048 + gslot * 8, &smem[2][w * 512]);

  for (int it = 0; it < 32; ++it) {
    __syncthreads();  // drains stage(it) [issued last iter], guards buffers
    const int cur = it & 1;
    if (it + 1 < 32) {  // stage(it+1): latency hides under compute(it)
      const int nxt = cur ^ 1, kt = (it + 1) * 64;
      gload_lds16(Kt + kbase + (size_t)(kt + row_st) * 64 + gslot * 8,
                  &smem[nxt][w * 512]);
      gload_lds16(VT + vbase + (size_t)row_st * 2048 + kt + gslot * 8,
                  &smem[2 + nxt][w * 512]);
    }

    // QK^T swapped: accS[t][reg] = S^T[k=32t+crow(reg,hi)][q=ql]
    f32x16 accS[2];
#pragma unroll
    for (int t = 0; t < 2; t++) {
#pragma unroll
      for (int r = 0; r < 16; r++) accS[t][r] = 0.f;
#pragma unroll
      for (int ks = 0; ks < 4; ks++) {
        const int row = 32 * t + ql;
        const int cs = (2 * ks + hi) ^ (lane & 7);
        short8 kf = *reinterpret_cast<const short8*>(&smem[cur][row * 64 + cs * 8]);
        accS[t] =
            __builtin_amdgcn_mfma_f32_32x32x16_bf16(kf, qf[ks], accS[t], 0, 0, 0);
      }
    }

    // in-register online softmax (log2 units), max3 tree
    float pmax = fmaxf(accS[0][0], accS[0][1]);
#pragma unroll
    for (int r = 2; r < 16; r += 2) pmax = fm3(pmax, accS[0][r], accS[0][r + 1]);
#pragma unroll
    for (int r = 0; r < 16; r += 2) pmax = fm3(pmax, accS[1][r], accS[1][r + 1]);
    pmax = fmaxf(pmax, __shfl_xor(pmax, 32, 64));
    if (__any(pmax - m > 11.0f)) {  // defer-max: skip rescale when growth small
      const float mn = fmaxf(m, pmax);
      const float al = exp2f(m - mn);
      m = mn;
      l *= al;
#pragma unroll
      for (int dt = 0; dt < 2; dt++)
#pragma unroll
        for (int r = 0; r < 16; r++) accO[dt][r] *= al;
    }
    float s = 0.f;
#pragma unroll
    for (int t = 0; t < 2; t++)
#pragma unroll
      for (int r = 0; r < 16; r++) {
        const float p = exp2f(accS[t][r] - m);
        accS[t][r] = p;
        s += p;
      }
    s += __shfl_xor(s, 32, 64);
    l += s;

    // PV: accO[dt] += V^T x P, k-steps of 16
#pragma unroll
    for (int ss = 0; ss < 4; ss++) {
      const int t = ss >> 1, base = (ss & 1) * 8;
      unsigned w01 = cvtpk_bf16(accS[t][base + 0], accS[t][base + 1]);
      unsigned w23 = cvtpk_bf16(accS[t][base + 2], accS[t][base + 3]);
      unsigned w45 = cvtpk_bf16(accS[t][base + 4], accS[t][base + 5]);
      unsigned w67 = cvtpk_bf16(accS[t][base + 6], accS[t][base + 7]);
      pl32swap(w01, w45);  // -> j={0,1} / {4,5}, k = 8*hi + j
      pl32swap(w23, w67);  // -> j={2,3} / {6,7}
      uint4 pau = {w01, w23, w45, w67};
      short8 pa = *reinterpret_cast<short8*>(&pau);
#pragma unroll
      for (int dt = 0; dt < 2; dt++) {
        const int row = 32 * dt + ql;
        const int cs = (2 * ss + hi) ^ (lane & 7);
        short8 vf =
            *reinterpret_cast<const short8*>(&smem[2 + cur][row * 64 + cs * 8]);
        accO[dt] =
            __builtin_amdgcn_mfma_f32_32x32x16_bf16(vf, pa, accO[dt], 0, 0, 0);
      }
    }
  }

  // epilogue: O^T regs -> LDS transpose (swizzled) -> coalesced global
  __syncthreads();
  bf16* tw = &smem[0][0] + w * 2048;  // 4KB per warp, 8 warps = all 32KB
  const float inv = 1.0f / l;
#pragma unroll
  for (int dt = 0; dt < 2; dt++)
#pragma unroll
    for (int g = 0; g < 4; g++) {
      unsigned wa = cvtpk_bf16(accO[dt][4 * g + 0] * inv, accO[dt][4 * g + 1] * inv);
      unsigned wb = cvtpk_bf16(accO[dt][4 * g + 2] * inv, accO[dt][4 * g + 3] * inv);
      const int c = (4 * dt + g) ^ (ql & 7);
      uint2 val = {wa, wb};
      *reinterpret_cast<uint2*>(tw + ql * 64 + c * 8 + hi * 4) = val;
    }
  __syncthreads();
  const int qr = lane >> 1, half = lane & 1;
  const size_t orow = (((size_t)b * 2048 + q0 + w * 32 + qr) * 16 + h) * 64;
#pragma unroll
  for (int i = 0; i < 4; i++) {
    const int c2 = (half * 4 + i) ^ (qr & 7);
    short8 v = *reinterpret_cast<const short8*>(tw + qr * 64 + c2 * 8);
    *reinterpret_cast<short8*>(Ctx + orow + half * 32 + i * 8) = v;
  }
}

// ================================================================ launch
// Workspace layout (72 MB total, lifetime-reused):
//   [ 0,16) MB  xb   (x in bf16)           -> reused as Qr after fused QKV GEMM
//   [16,24) MB  WTq/WTk/WTv/WTo (2 MB each; WTq..WTv contiguous = fused BT)
//   [24,40) MB  Yq                         -> reused as Kr after RoPE-Q
//   [40,56) MB  Yk                         -> reused as VT after RoPE-K
//   [56,72) MB  Yv                         -> reused as Ctx after V-trans
extern "C" void kernel_launch(void* const* d_in, const int* in_sizes, int n_in,
                              void* d_out, int out_size, void* d_ws, size_t ws_size,
                              hipStream_t stream) {
  const float* x = (const float*)d_in[0];
  const int* positions = (const int*)d_in[1];
  const float* Wq = (const float*)d_in[2];
  const float* bq = (const float*)d_in[3];
  const float* Wk = (const float*)d_in[4];
  const float* bk = (const float*)d_in[5];
  const float* Wv = (const float*)d_in[6];
  const float* bv = (const float*)d_in[7];
  const float* Wo = (const float*)d_in[8];
  const float* bo = (const float*)d_in[9];
  const float* q_scale = (const float*)d_in[10];
  const float* k_scale = (const float*)d_in[11];
  const float* v_scale = (const float*)d_in[12];
  const float* o_scale = (const float*)d_in[13];
  float* out = (float*)d_out;

  char* ws = (char*)d_ws;
  bf16* xb  = (bf16*)(ws);                 // 16 MB
  bf16* WTq = (bf16*)(ws + (16u << 20));   // 4 x 2 MB (q,k,v contiguous)
  bf16* WTk = WTq + (1u << 20);
  bf16* WTv = WTk + (1u << 20);
  bf16* WTo = WTv + (1u << 20);
  bf16* Yq  = (bf16*)(ws + (24u << 20));
  bf16* Yk  = (bf16*)(ws + (40u << 20));
  bf16* Yv  = (bf16*)(ws + (56u << 20));
  bf16* Qr  = xb;   // xb dead after fused QKV GEMM
  bf16* Kr  = Yq;   // Yq dead after RoPE-Q
  bf16* VT  = Yk;   // Yk dead after RoPE-K
  bf16* Ctx = Yv;   // Yv dead after V-transpose

  const int M = 8192, N = 1024, K = 1024;

  k_convert<<<8192, 256, 0, stream>>>(x, xb, M * K / 4);
  k_wtrans<<<dim3(16, 16, 4), 256, 0, stream>>>(Wq, Wk, Wv, Wo, WTq, WTk, WTv, WTo);

  // fused QKV projection: N = 3072 (Yq,Yk,Yv spaced 8M elems in ws)
  k_gemm_qkv<<<dim3(64, 24), 256, 0, stream>>>(xb, WTq, bq, bk, bv,
                                               q_scale, k_scale, v_scale, Yq);

  // Q pre-scale: (1/sqrt(64)) * log2(e) so attention uses exp2 directly
  k_rope<<<2048, 256, 0, stream>>>(Yq, positions, Qr, 0.18033688011112042f);
  k_rope<<<2048, 256, 0, stream>>>(Yk, positions, Kr, 1.0f);
  k_vtrans<<<dim3(32, 64), 256, 0, stream>>>(Yv, VT);

  k_attn<<<dim3(8, 64), 512, 0, stream>>>(Qr, Kr, VT, Ctx);

  k_gemm_bt<<<dim3(64, 8), 256, 0, stream>>>(Ctx, WTo, bo, o_scale, out, M, N, K);
}